// Round 1
// baseline (512.433 us; speedup 1.0000x reference)
//
#include <hip/hip_runtime.h>
#include <math.h>

#define NN 64
#define CC 160
#define LL 4096
#define DD 160
#define MM 6
#define CHUNKS 8

using f32x4 = __attribute__((ext_vector_type(4))) float;
using s16x8 = __attribute__((ext_vector_type(8))) short;

__device__ __forceinline__ float bf2f(unsigned short u) {
  union { unsigned int i; float f; } v; v.i = ((unsigned int)u) << 16; return v.f;
}
__device__ __forceinline__ unsigned short f2bf(float f) {
  union { float f; unsigned int i; } v; v.f = f;
  unsigned int r = v.i + 0x7fffu + ((v.i >> 16) & 1u);
  return (unsigned short)(r >> 16);
}

// ---------------- K_init: tau, Bpack (Wk|Wv in MFMA B-frag layout), q1 ----------------
__global__ __launch_bounds__(256) void k_init(
    const float* log_tau, const float* slots_init,
    const float* q_g, const float* q_b, const float* Wq,
    const float* Wk, const float* Wv,
    unsigned short* Bpack, float* qbuf, float* scal) {
  __shared__ float ln[MM * DD];
  __shared__ float mu_s[MM], rs_s[MM];
  int tid = threadIdx.x;
  if (tid == 0) {
    float x = log_tau[0];
    float sp = (x > 20.f) ? x : log1pf(expf(x));
    float tau = sp + 0.5f;
    scal[0] = (1.0f / sqrtf((float)DD)) / tau;
  }
  // Bpack[ct][kt][lane][j] = W[(kt*32 + (lane>>4)*8 + j)][ct*16 + (lane&15)], W = [Wk | Wv]
  for (int idx = tid; idx < 20 * 5 * 64 * 8; idx += 256) {
    int j = idx & 7;
    int lane = (idx >> 3) & 63;
    int ctkt = idx >> 9;          // ct*5 + kt
    int kt = ctkt % 5, ct = ctkt / 5;
    int krow = kt * 32 + (lane >> 4) * 8 + j;
    int col = ct * 16 + (lane & 15);
    float v = (col < DD) ? Wk[krow * DD + col] : Wv[krow * DD + (col - DD)];
    Bpack[idx] = f2bf(v);
  }
  // q1 = LN(slots_init) @ Wq   (shared across all n for iteration 1)
  if (tid < MM) {
    float s = 0.f, ss = 0.f;
    for (int i = 0; i < DD; i++) { float x = slots_init[tid * DD + i]; s += x; ss += x * x; }
    float mu = s / DD;
    float var = ss / DD - mu * mu;
    mu_s[tid] = mu; rs_s[tid] = rsqrtf(var + 1e-5f);
  }
  __syncthreads();
  for (int o = tid; o < MM * DD; o += 256) {
    int m = o / DD, d = o % DD;
    ln[o] = (slots_init[o] - mu_s[m]) * rs_s[m] * q_g[d] + q_b[d];
  }
  __syncthreads();
  for (int o = tid; o < MM * DD; o += 256) {
    int m = o / DD, d = o % DD;
    float acc = 0.f;
    for (int i = 0; i < DD; i++) acc += ln[m * DD + i] * Wq[i * DD + d];
    qbuf[o] = acc;
  }
}

// ---------------- K_kv: per-token LN + bf16 MFMA projection -> kbuf/vbuf (bf16) ----------------
__global__ __launch_bounds__(256) void k_kv(
    const float* feat, const float* kv_g, const float* kv_b,
    const unsigned short* Bpack, unsigned short* kbuf, unsigned short* vbuf) {
  int b = blockIdx.x;
  int n = b >> 6, l0 = (b & 63) << 6;   // 64 tokens per block
  int tid = threadIdx.x;
  int lane = tid & 63, g = tid >> 6;    // g = wave id; wave g loads channels [g*40, g*40+40)
  __shared__ __align__(16) unsigned short Apack[4 * 5 * 64 * 8]; // A in MFMA frag layout
  __shared__ float partial[4][64][2];
  __shared__ float mean_s[64], rstd_s[64];
  const int l = lane;                   // token within tile
  float rv[40];
  float s = 0.f, ss = 0.f;
  const float* fp = feat + ((size_t)(n * CC + g * 40)) * LL + l0 + l;
#pragma unroll
  for (int i = 0; i < 40; i++) {
    float x = fp[(size_t)i * LL];
    rv[i] = x; s += x; ss += x * x;
  }
  partial[g][l][0] = s; partial[g][l][1] = ss;
  __syncthreads();
  if (tid < 64) {
    float S = 0.f, SS = 0.f;
    for (int gg = 0; gg < 4; gg++) { S += partial[gg][tid][0]; SS += partial[gg][tid][1]; }
    float mu = S / CC;
    float var = SS / CC - mu * mu;
    mean_s[tid] = mu; rstd_s[tid] = rsqrtf(var + 1e-5f);
  }
  __syncthreads();
  float mu = mean_s[l], rs = rstd_s[l];
  int mt = l >> 4, lfbase = l & 15;
#pragma unroll
  for (int q5 = 0; q5 < 5; q5++) {
    int c0 = g * 40 + q5 * 8;           // always a multiple of 8
    int kt = c0 >> 5, hi = (c0 >> 3) & 3;
    unsigned short pk[8];
#pragma unroll
    for (int j = 0; j < 8; j++) {
      int c = c0 + j;
      float a = (rv[q5 * 8 + j] - mu) * rs * kv_g[c] + kv_b[c];
      pk[j] = f2bf(a);
    }
    int lf = lfbase + (hi << 4);
    *(uint4*)&Apack[((mt * 5 + kt) * 64 + lf) * 8] = *(const uint4*)pk;
  }
  __syncthreads();
  // MFMA: wave g computes output col-tiles ct = g*5 .. g*5+4 (16 cols each) over 64 tokens
  for (int ct5 = 0; ct5 < 5; ct5++) {
    int ct = g * 5 + ct5;
    f32x4 acc0 = {0.f, 0.f, 0.f, 0.f}, acc1 = acc0, acc2 = acc0, acc3 = acc0;
#pragma unroll
    for (int kt = 0; kt < 5; kt++) {
      s16x8 bfr = *(const s16x8*)&Bpack[((ct * 5 + kt) * 64 + lane) * 8];
      s16x8 a0 = *(const s16x8*)&Apack[((0 * 5 + kt) * 64 + lane) * 8];
      s16x8 a1 = *(const s16x8*)&Apack[((1 * 5 + kt) * 64 + lane) * 8];
      s16x8 a2 = *(const s16x8*)&Apack[((2 * 5 + kt) * 64 + lane) * 8];
      s16x8 a3 = *(const s16x8*)&Apack[((3 * 5 + kt) * 64 + lane) * 8];
      acc0 = __builtin_amdgcn_mfma_f32_16x16x32_bf16(a0, bfr, acc0, 0, 0, 0);
      acc1 = __builtin_amdgcn_mfma_f32_16x16x32_bf16(a1, bfr, acc1, 0, 0, 0);
      acc2 = __builtin_amdgcn_mfma_f32_16x16x32_bf16(a2, bfr, acc2, 0, 0, 0);
      acc3 = __builtin_amdgcn_mfma_f32_16x16x32_bf16(a3, bfr, acc3, 0, 0, 0);
    }
    int col = ct * 16 + (lane & 15);
    unsigned short* obuf = (col < DD) ? kbuf : vbuf;
    int ocol = (col < DD) ? col : col - DD;
#pragma unroll
    for (int mtl = 0; mtl < 4; mtl++) {
      f32x4 a = (mtl == 0) ? acc0 : (mtl == 1) ? acc1 : (mtl == 2) ? acc2 : acc3;
#pragma unroll
      for (int r = 0; r < 4; r++) {
        int row = mtl * 16 + (lane >> 4) * 4 + r;   // D: col=lane&15, row=(lane>>4)*4+r
        obuf[((size_t)(n * LL + l0 + row)) * DD + ocol] = f2bf(a[r]);
      }
    }
  }
}

// ---------------- K_attn: logits -> softmax(over slots) -> S,U partials ----------------
template <bool QPN, bool WATT>
__global__ __launch_bounds__(256) void k_attn(
    const unsigned short* kbuf, const unsigned short* vbuf,
    const float* qbuf, const float* scal,
    float* Upart, float* Spart, float* attn_out) {
  int b = blockIdx.x;
  int n = b >> 3, c8 = b & 7;           // 512 tokens per block, 4 sub-chunks of 128
  int tid = threadIdx.x;
  __shared__ __align__(16) unsigned short ktile[128][168];  // +8 pad
  __shared__ float att[128][6];
  __shared__ float qlds[MM * DD];
  __shared__ float sred[128][6];
  const float* qsrc = QPN ? (qbuf + (size_t)n * MM * DD) : qbuf;
  for (int o = tid; o < MM * DD; o += 256) qlds[o] = qsrc[o];
  float inv_st = scal[0];
  float Uacc[6] = {0, 0, 0, 0, 0, 0};
  float Sacc[6] = {0, 0, 0, 0, 0, 0};
  int tl = tid >> 1, half = tid & 1;
  __syncthreads();
  for (int sc = 0; sc < 4; sc++) {
    int tok0 = c8 * 512 + sc * 128;
    {
      const unsigned short* src = kbuf + ((size_t)(n * LL + tok0)) * DD;
      for (int i = tid; i < 128 * 20; i += 256) {
        int row = i / 20, u = i % 20;
        uint4 vld = *(const uint4*)(src + (size_t)row * DD + u * 8);
        *(uint4*)&ktile[row][u * 8] = vld;
      }
    }
    __syncthreads();
    // phase 1: 2 threads per token, 3 slots each
    {
      int m0 = half * 3;
      float l0a = 0.f, l1a = 0.f, l2a = 0.f;
      const float* q0 = &qlds[m0 * DD];
      const float* q1 = &qlds[(m0 + 1) * DD];
      const float* q2 = &qlds[(m0 + 2) * DD];
#pragma unroll 5
      for (int u = 0; u < 20; u++) {
        uint4 kv = *(const uint4*)&ktile[tl][u * 8];
        const unsigned short* kp = (const unsigned short*)&kv;
#pragma unroll
        for (int j = 0; j < 8; j++) {
          float kf = bf2f(kp[j]);
          int c = u * 8 + j;
          l0a += kf * q0[c]; l1a += kf * q1[c]; l2a += kf * q2[c];
        }
      }
      l0a *= inv_st; l1a *= inv_st; l2a *= inv_st;
      float o0 = __shfl_xor(l0a, 1);
      float o1 = __shfl_xor(l1a, 1);
      float o2 = __shfl_xor(l2a, 1);
      float lg[6];
      if (half == 0) { lg[0] = l0a; lg[1] = l1a; lg[2] = l2a; lg[3] = o0; lg[4] = o1; lg[5] = o2; }
      else           { lg[0] = o0;  lg[1] = o1;  lg[2] = o2;  lg[3] = l0a; lg[4] = l1a; lg[5] = l2a; }
      float mx = lg[0];
#pragma unroll
      for (int m = 1; m < 6; m++) mx = fmaxf(mx, lg[m]);
      float e[6], sum = 0.f;
#pragma unroll
      for (int m = 0; m < 6; m++) { e[m] = __expf(lg[m] - mx); sum += e[m]; }
      float inv = 1.0f / sum;
      if (half == 0) {
#pragma unroll
        for (int m = 0; m < 6; m++) {
          float a = e[m] * inv;
          att[tl][m] = a;
          Sacc[m] += a;
          if (WATT) attn_out[((size_t)(n * MM + m)) * LL + tok0 + tl] = a;
        }
      }
    }
    __syncthreads();
    // phase 2: d-parallel U accumulation (threads 0..159)
    if (tid < DD) {
      const unsigned short* vsrc = vbuf + ((size_t)(n * LL + tok0)) * DD + tid;
#pragma unroll 4
      for (int t = 0; t < 128; t++) {
        float vv = bf2f(vsrc[(size_t)t * DD]);
#pragma unroll
        for (int m = 0; m < 6; m++) Uacc[m] += att[t][m] * vv;
      }
    }
    __syncthreads();
  }
  if (half == 0) {
#pragma unroll
    for (int m = 0; m < 6; m++) sred[tl][m] = Sacc[m];
  }
  __syncthreads();
  if (tid < 6) {
    float ssum = 0.f;
    for (int t = 0; t < 128; t++) ssum += sred[t][tid];
    Spart[b * 6 + tid] = ssum;
  }
  if (tid < DD) {
#pragma unroll
    for (int m = 0; m < 6; m++) Upart[((size_t)b * 6 + m) * DD + tid] = Uacc[m];
  }
}

// ---------------- K_slot: slots += U/S, LN, MLP, (q for next iter | final write) ----------------
template <bool FIRST, bool LAST>
__global__ __launch_bounds__(256) void k_slot(
    const float* slots_init, const float* Upart, const float* Spart,
    const float* out_g, const float* out_b,
    const float* W1, const float* b1, const float* W2, const float* b2,
    const float* q_g, const float* q_b, const float* Wq,
    float* slotbuf, float* qbuf, float* Sfin, float* out_slots) {
  int n = blockIdx.x;
  int tid = threadIdx.x;
  __shared__ float s0[MM * DD];
  __shared__ float h[MM * 320];
  __shared__ float Sv[MM], mu_s[MM], rs_s[MM];
  if (tid < MM) {
    float s = 0.f;
    for (int p = 0; p < CHUNKS; p++) s += Spart[(n * CHUNKS + p) * 6 + tid];
    s = fmaxf(s, 1e-6f);
    Sv[tid] = s;
    if (LAST) Sfin[n * 6 + tid] = s;
  }
  __syncthreads();
  for (int o = tid; o < MM * DD; o += 256) {
    int m = o / DD, d = o % DD;
    float u = 0.f;
    for (int p = 0; p < CHUNKS; p++) u += Upart[((size_t)(n * CHUNKS + p) * 6 + m) * DD + d];
    float prev = FIRST ? slots_init[o] : slotbuf[(size_t)n * MM * DD + o];
    s0[o] = prev + u / Sv[m];
  }
  __syncthreads();
  if (tid < MM) {
    float s = 0.f, ss = 0.f;
    for (int i = 0; i < DD; i++) { float x = s0[tid * DD + i]; s += x; ss += x * x; }
    float mu = s / DD, var = ss / DD - mu * mu;
    mu_s[tid] = mu; rs_s[tid] = rsqrtf(var + 1e-5f);
  }
  __syncthreads();
  for (int o = tid; o < MM * DD; o += 256) {
    int m = o / DD, d = o % DD;
    s0[o] = (s0[o] - mu_s[m]) * rs_s[m] * out_g[d] + out_b[d];
  }
  __syncthreads();
  for (int o = tid; o < MM * 320; o += 256) {
    int m = o / 320, j = o % 320;
    float acc = b1[j];
    for (int d = 0; d < DD; d++) acc += s0[m * DD + d] * W1[d * 320 + j];
    h[o] = 0.5f * acc * (1.0f + erff(acc * 0.70710678118f));  // exact GELU
  }
  __syncthreads();
  for (int o = tid; o < MM * DD; o += 256) {
    int m = o / DD, d = o % DD;
    float acc = b2[d];
    for (int j = 0; j < 320; j++) acc += h[m * 320 + j] * W2[j * DD + d];
    float val = s0[o] + acc;
    slotbuf[(size_t)n * MM * DD + o] = val;
    if (LAST) out_slots[(size_t)n * MM * DD + o] = val;
    s0[o] = val;
  }
  if (!LAST) {
    __syncthreads();
    if (tid < MM) {
      float s = 0.f, ss = 0.f;
      for (int i = 0; i < DD; i++) { float x = s0[tid * DD + i]; s += x; ss += x * x; }
      float mu = s / DD, var = ss / DD - mu * mu;
      mu_s[tid] = mu; rs_s[tid] = rsqrtf(var + 1e-5f);
    }
    __syncthreads();
    for (int o = tid; o < MM * DD; o += 256) {
      int m = o / DD, d = o % DD;
      h[o] = (s0[o] - mu_s[m]) * rs_s[m] * q_g[d] + q_b[d];
    }
    __syncthreads();
    for (int o = tid; o < MM * DD; o += 256) {
      int m = o / DD, d = o % DD;
      float acc = 0.f;
      for (int i = 0; i < DD; i++) acc += h[m * DD + i] * Wq[i * DD + d];
      qbuf[(size_t)n * MM * DD + o] = acc;
    }
  }
}

// ---------------- K_norm: attn_map = attn / S ----------------
__global__ __launch_bounds__(256) void k_norm(float* attn, const float* Sfin) {
  int idx = blockIdx.x * 256 + threadIdx.x;
  size_t base = (size_t)idx * 4;
  int nm = (int)(base / LL);            // n*6+m (rows are 4096 long, 4-aligned)
  float s = Sfin[nm];
  float4 v = *(float4*)(attn + base);
  v.x /= s; v.y /= s; v.z /= s; v.w /= s;
  *(float4*)(attn + base) = v;
}

extern "C" void kernel_launch(void* const* d_in, const int* in_sizes, int n_in,
                              void* d_out, int out_size, void* d_ws, size_t ws_size,
                              hipStream_t stream) {
  const float* feat       = (const float*)d_in[0];
  const float* slots_init = (const float*)d_in[1];
  const float* log_tau    = (const float*)d_in[2];
  const float* kv_g       = (const float*)d_in[3];
  const float* kv_b       = (const float*)d_in[4];
  const float* Wk         = (const float*)d_in[5];
  const float* Wv         = (const float*)d_in[6];
  const float* q_g        = (const float*)d_in[7];
  const float* q_b        = (const float*)d_in[8];
  const float* Wq         = (const float*)d_in[9];
  const float* out_g      = (const float*)d_in[10];
  const float* out_b      = (const float*)d_in[11];
  const float* W1         = (const float*)d_in[12];
  const float* b1         = (const float*)d_in[13];
  const float* W2         = (const float*)d_in[14];
  const float* b2         = (const float*)d_in[15];
  float* out = (float*)d_out;
  float* out_attn = out + NN * MM * DD;

  // workspace layout
  size_t kv_elems = (size_t)NN * LL * DD;                 // 41.9M bf16 each
  unsigned short* kbuf  = (unsigned short*)d_ws;
  unsigned short* vbuf  = kbuf + kv_elems;
  unsigned short* Bpack = vbuf + kv_elems;                // 51200 bf16
  float* qbuf    = (float*)(Bpack + 20 * 5 * 64 * 8);     // [64][6][160]
  float* slotbuf = qbuf + NN * MM * DD;
  float* Upart   = slotbuf + NN * MM * DD;                // [512][6][160]
  float* Spart   = Upart + (size_t)NN * CHUNKS * MM * DD;
  float* Sfin    = Spart + NN * CHUNKS * MM;
  float* scal    = Sfin + NN * MM;
  size_t required = (size_t)((char*)(scal + 8) - (char*)d_ws);
  if (ws_size < required) return;  // insufficient scratch: fail clean (output stays poisoned)

  k_init<<<1, 256, 0, stream>>>(log_tau, slots_init, q_g, q_b, Wq, Wk, Wv, Bpack, qbuf, scal);
  k_kv<<<NN * 64, 256, 0, stream>>>(feat, kv_g, kv_b, Bpack, kbuf, vbuf);
  k_attn<false, false><<<NN * CHUNKS, 256, 0, stream>>>(kbuf, vbuf, qbuf, scal, Upart, Spart, out_attn);
  k_slot<true, false><<<NN, 256, 0, stream>>>(slots_init, Upart, Spart, out_g, out_b, W1, b1, W2, b2,
                                              q_g, q_b, Wq, slotbuf, qbuf, Sfin, out);
  k_attn<true, true><<<NN * CHUNKS, 256, 0, stream>>>(kbuf, vbuf, qbuf, scal, Upart, Spart, out_attn);
  k_slot<false, true><<<NN, 256, 0, stream>>>(slots_init, Upart, Spart, out_g, out_b, W1, b1, W2, b2,
                                              q_g, q_b, Wq, slotbuf, qbuf, Sfin, out);
  k_norm<<<(NN * MM * LL) / 1024, 256, 0, stream>>>(out_attn, Sfin);
}

// Round 2
// 348.787 us; speedup vs baseline: 1.4692x; 1.4692x over previous
//
#include <hip/hip_runtime.h>
#include <math.h>

#define NN 64
#define CC 160
#define LL 4096
#define DD 160
#define MM 6
#define NCHUNK 16   // chunks per image; each chunk = 256 tokens (4 tiles of 64)

__device__ __forceinline__ float bf2f(unsigned short u) {
  union { unsigned int i; float f; } v; v.i = ((unsigned int)u) << 16; return v.f;
}
__device__ __forceinline__ unsigned short f2bf(float f) {
  union { float f; unsigned int i; } v; v.f = f;
  unsigned int r = v.i + 0x7fffu + ((v.i >> 16) & 1u);
  return (unsigned short)(r >> 16);
}

// ---------------- k_init: scal = (d^-0.5 / tau); Wkq1 = scal * Wk @ q1^T ----------------
// grid 16, block 256. Block bi computes Wkq1 rows c in [bi*10, bi*10+10).
__global__ __launch_bounds__(256) void k_init(
    const float* log_tau, const float* slots_init, const float* q_g, const float* q_b,
    const float* Wq, const float* Wk, float* Wkq1, float* scal) {
  __shared__ float ln[MM * DD];
  __shared__ float qv[MM * DD];
  __shared__ float mu_s[MM], rs_s[MM];
  int tid = threadIdx.x;
  float x = log_tau[0];
  float sp = (x > 20.f) ? x : log1pf(expf(x));
  float scv = (1.0f / sqrtf((float)DD)) / (sp + 0.5f);
  if (blockIdx.x == 0 && tid == 0) scal[0] = scv;
  if (tid < MM) {
    float s = 0.f, ss = 0.f;
    for (int i = 0; i < DD; i++) { float v = slots_init[tid * DD + i]; s += v; ss += v * v; }
    float mu = s / DD, var = ss / DD - mu * mu;
    mu_s[tid] = mu; rs_s[tid] = rsqrtf(var + 1e-5f);
  }
  __syncthreads();
  for (int o = tid; o < MM * DD; o += 256) {
    int m = o / DD, d = o % DD;
    ln[o] = (slots_init[o] - mu_s[m]) * rs_s[m] * q_g[d] + q_b[d];
  }
  __syncthreads();
  for (int o = tid; o < MM * DD; o += 256) {
    int m = o / DD, d = o % DD;
    float acc = 0.f;
    for (int i = 0; i < DD; i++) acc += ln[m * DD + i] * Wq[i * DD + d];
    qv[o] = acc;
  }
  __syncthreads();
  for (int o = tid; o < 60; o += 256) {
    int c = blockIdx.x * 10 + o / 6, m = o % 6;
    float acc = 0.f;
    for (int d = 0; d < DD; d++) acc += Wk[c * DD + d] * qv[m * DD + d];
    Wkq1[c * 6 + m] = scv * acc;
  }
}

// ---------------- k_pass: fused LN + logits + softmax + weighted-token aggregation ----------------
// grid = 64*16 (n, chunk of 256 tokens), block 256 (4 waves). 4 tiles of 64 tokens.
template <bool ITER2>
__global__ __launch_bounds__(256) void k_pass(
    const float* feat, const float* kv_g, const float* kv_b,
    const float* Wkq,                       // ITER2: [n][160][6]; else shared [160][6]
    float* Apart, float* Spart, float* attn_out) {
  int b = blockIdx.x;
  int n = b >> 4, ch = b & 15;
  int tid = threadIdx.x;
  int lane = tid & 63, g = tid >> 6;
  __shared__ __align__(16) unsigned short xln[64][168];   // bf16 LN'd tile, 336B row stride
  __shared__ float att[64][6];
  __shared__ float wkq_s[160][6];
  __shared__ float part[4][64][2];
  __shared__ float mu_s[64], rs_s[64];
  __shared__ float sred[64][6];

  const float* wsrc = ITER2 ? (Wkq + (size_t)n * DD * 6) : Wkq;
  for (int o = tid; o < DD * 6; o += 256) ((float*)wkq_s)[o] = wsrc[o];

  float Aacc[6] = {0, 0, 0, 0, 0, 0};
  float Sacc[6] = {0, 0, 0, 0, 0, 0};
  __syncthreads();

  for (int t4 = 0; t4 < 4; t4++) {
    int tok0 = ch * 256 + t4 * 64;
    // ---- load 40 channels x 64 tokens per wave; LN stats ----
    const float* fp = feat + ((size_t)(n * CC + g * 40)) * LL + tok0 + lane;
    float rv[40];
    float s = 0.f, ss = 0.f;
#pragma unroll
    for (int i = 0; i < 40; i++) {
      float v = fp[(size_t)i * LL];
      rv[i] = v; s += v; ss += v * v;
    }
    part[g][lane][0] = s; part[g][lane][1] = ss;
    __syncthreads();
    if (tid < 64) {
      float S = 0.f, SS = 0.f;
      for (int gg = 0; gg < 4; gg++) { S += part[gg][tid][0]; SS += part[gg][tid][1]; }
      float mu = S / CC, var = SS / CC - mu * mu;
      mu_s[tid] = mu; rs_s[tid] = rsqrtf(var + 1e-5f);
    }
    __syncthreads();
    // ---- normalize + pack bf16 to LDS [t][c] ----
    {
      float mu = mu_s[lane], rs = rs_s[lane];
#pragma unroll
      for (int q5 = 0; q5 < 5; q5++) {
        unsigned short pk[8];
#pragma unroll
        for (int j = 0; j < 8; j++) {
          int c = g * 40 + q5 * 8 + j;
          float a = (rv[q5 * 8 + j] - mu) * rs * kv_g[c] + kv_b[c];
          pk[j] = f2bf(a);
        }
        *(uint4*)&xln[lane][g * 40 + q5 * 8] = *(const uint4*)pk;
      }
    }
    __syncthreads();
    // ---- phase 1: logits (2 threads/token, 80 channels each) + softmax over slots ----
    if (tid < 128) {
      int tl = tid >> 1, hf = tid & 1;
      const unsigned short* xrow = &xln[tl][hf * 80];
      float lg[6] = {0, 0, 0, 0, 0, 0};
#pragma unroll
      for (int u = 0; u < 10; u++) {
        uint4 kv = *(const uint4*)(xrow + u * 8);
        const unsigned short* kp = (const unsigned short*)&kv;
#pragma unroll
        for (int j = 0; j < 8; j++) {
          float kf = bf2f(kp[j]);
          const float* wr = &wkq_s[hf * 80 + u * 8 + j][0];
#pragma unroll
          for (int m = 0; m < 6; m++) lg[m] += kf * wr[m];
        }
      }
#pragma unroll
      for (int m = 0; m < 6; m++) lg[m] += __shfl_xor(lg[m], 1);
      float mx = lg[0];
#pragma unroll
      for (int m = 1; m < 6; m++) mx = fmaxf(mx, lg[m]);
      float e[6], sum = 0.f;
#pragma unroll
      for (int m = 0; m < 6; m++) { e[m] = __expf(lg[m] - mx); sum += e[m]; }
      float inv = 1.0f / sum;
      if (hf == 0) {
#pragma unroll
        for (int m = 0; m < 6; m++) {
          float a = e[m] * inv;
          att[tl][m] = a;
          Sacc[m] += a;
          if (ITER2) attn_out[((size_t)(n * MM + m)) * LL + tok0 + tl] = a;
        }
      }
    }
    __syncthreads();
    // ---- phase 2: c-parallel weighted-token accumulation ----
    if (tid < DD) {
#pragma unroll 4
      for (int t = 0; t < 64; t++) {
        float xv = bf2f(xln[t][tid]);
        float a0 = att[t][0], a1 = att[t][1], a2 = att[t][2];
        float a3 = att[t][3], a4 = att[t][4], a5 = att[t][5];
        Aacc[0] += a0 * xv; Aacc[1] += a1 * xv; Aacc[2] += a2 * xv;
        Aacc[3] += a3 * xv; Aacc[4] += a4 * xv; Aacc[5] += a5 * xv;
      }
    }
    __syncthreads();
  }
  // ---- write partials ----
  if (tid < DD) {
#pragma unroll
    for (int m = 0; m < 6; m++) Apart[((size_t)b * 6 + m) * DD + tid] = Aacc[m];
  }
  if (tid < 128 && (tid & 1) == 0) {
#pragma unroll
    for (int m = 0; m < 6; m++) sred[tid >> 1][m] = Sacc[m];
  }
  __syncthreads();
  if (tid < 6) {
    float s = 0.f;
    for (int t = 0; t < 64; t++) s += sred[t][tid];
    Spart[b * 6 + tid] = s;
  }
}

// ---------------- k_slot: reduce partials, U = A@Wv, slot update, LN, MLP, next Wkq ----------------
template <bool FIRST, bool LAST>
__global__ __launch_bounds__(256) void k_slot(
    const float* slots_init, const float* Apart, const float* Spart, const float* Wv,
    const float* out_g, const float* out_b,
    const float* W1, const float* b1, const float* W2, const float* b2,
    const float* q_g, const float* q_b, const float* Wq, const float* Wk, const float* scal,
    float* slotbuf, float* Wkq2, float* Sfin, float* out_slots) {
  int n = blockIdx.x;
  int tid = threadIdx.x;
  __shared__ float a_s[MM * DD];
  __shared__ float s0[MM * DD];
  __shared__ float h[MM * 320];
  __shared__ float Sv[MM], mu_s[MM], rs_s[MM];
  if (tid < MM) {
    float s = 0.f;
    for (int p = 0; p < NCHUNK; p++) s += Spart[(n * NCHUNK + p) * 6 + tid];
    float sc = fmaxf(s, 1e-6f);
    Sv[tid] = sc;
    if (LAST) Sfin[n * 6 + tid] = sc;
  }
  for (int o = tid; o < MM * DD; o += 256) {
    int m = o / DD, c = o % DD;
    float s = 0.f;
    for (int p = 0; p < NCHUNK; p++) s += Apart[((size_t)(n * NCHUNK + p) * 6 + m) * DD + c];
    a_s[o] = s;
  }
  __syncthreads();
  for (int o = tid; o < MM * DD; o += 256) {
    int m = o / DD, d = o % DD;
    float u = 0.f;
    for (int c = 0; c < DD; c++) u += a_s[m * DD + c] * Wv[c * DD + d];
    float prev = FIRST ? slots_init[o] : slotbuf[(size_t)n * MM * DD + o];
    s0[o] = prev + u / Sv[m];
  }
  __syncthreads();
  if (tid < MM) {
    float s = 0.f, ss = 0.f;
    for (int i = 0; i < DD; i++) { float x = s0[tid * DD + i]; s += x; ss += x * x; }
    float mu = s / DD, var = ss / DD - mu * mu;
    mu_s[tid] = mu; rs_s[tid] = rsqrtf(var + 1e-5f);
  }
  __syncthreads();
  for (int o = tid; o < MM * DD; o += 256) {
    int m = o / DD, d = o % DD;
    s0[o] = (s0[o] - mu_s[m]) * rs_s[m] * out_g[d] + out_b[d];
  }
  __syncthreads();
  for (int o = tid; o < MM * 320; o += 256) {
    int m = o / 320, j = o % 320;
    float acc = b1[j];
    for (int d = 0; d < DD; d++) acc += s0[m * DD + d] * W1[d * 320 + j];
    h[o] = 0.5f * acc * (1.0f + erff(acc * 0.70710678118f));  // exact GELU
  }
  __syncthreads();
  for (int o = tid; o < MM * DD; o += 256) {
    int m = o / DD, d = o % DD;
    float acc = b2[d];
    for (int j = 0; j < 320; j++) acc += h[m * 320 + j] * W2[j * DD + d];
    float val = s0[o] + acc;
    slotbuf[(size_t)n * MM * DD + o] = val;
    if (LAST) out_slots[(size_t)n * MM * DD + o] = val;
  }
  if (!LAST) {
    __syncthreads();
    // s0 must hold the final slot values for the q-LN: recompute store into s0
    for (int o = tid; o < MM * DD; o += 256) s0[o] = slotbuf[(size_t)n * MM * DD + o];
    __syncthreads();
    if (tid < MM) {
      float s = 0.f, ss = 0.f;
      for (int i = 0; i < DD; i++) { float x = s0[tid * DD + i]; s += x; ss += x * x; }
      float mu = s / DD, var = ss / DD - mu * mu;
      mu_s[tid] = mu; rs_s[tid] = rsqrtf(var + 1e-5f);
    }
    __syncthreads();
    for (int o = tid; o < MM * DD; o += 256) {
      int m = o / DD, d = o % DD;
      h[o] = (s0[o] - mu_s[m]) * rs_s[m] * q_g[d] + q_b[d];
    }
    __syncthreads();
    for (int o = tid; o < MM * DD; o += 256) {
      int m = o / DD, d = o % DD;
      float acc = 0.f;
      for (int i = 0; i < DD; i++) acc += h[m * DD + i] * Wq[i * DD + d];
      a_s[o] = acc;                                    // q2[m][d]
    }
    __syncthreads();
    float sc = scal[0];
    for (int o = tid; o < DD * 6; o += 256) {
      int c = o / 6, m = o % 6;
      float acc = 0.f;
      for (int d = 0; d < DD; d++) acc += Wk[c * DD + d] * a_s[m * DD + d];
      Wkq2[(size_t)n * DD * 6 + o] = sc * acc;
    }
  }
}

// ---------------- k_norm: attn_map = attn / Sfin ----------------
__global__ __launch_bounds__(256) void k_norm(float* attn, const float* Sfin) {
  int idx = blockIdx.x * 256 + threadIdx.x;
  size_t base = (size_t)idx * 4;
  int nm = (int)(base >> 12);           // rows are 4096 floats
  float s = Sfin[nm];
  float4 v = *(float4*)(attn + base);
  float inv = 1.0f / s;
  v.x *= inv; v.y *= inv; v.z *= inv; v.w *= inv;
  *(float4*)(attn + base) = v;
}

extern "C" void kernel_launch(void* const* d_in, const int* in_sizes, int n_in,
                              void* d_out, int out_size, void* d_ws, size_t ws_size,
                              hipStream_t stream) {
  const float* feat       = (const float*)d_in[0];
  const float* slots_init = (const float*)d_in[1];
  const float* log_tau    = (const float*)d_in[2];
  const float* kv_g       = (const float*)d_in[3];
  const float* kv_b       = (const float*)d_in[4];
  const float* Wk         = (const float*)d_in[5];
  const float* Wv         = (const float*)d_in[6];
  const float* q_g        = (const float*)d_in[7];
  const float* q_b        = (const float*)d_in[8];
  const float* Wq         = (const float*)d_in[9];
  const float* out_g      = (const float*)d_in[10];
  const float* out_b      = (const float*)d_in[11];
  const float* W1         = (const float*)d_in[12];
  const float* b1         = (const float*)d_in[13];
  const float* W2         = (const float*)d_in[14];
  const float* b2         = (const float*)d_in[15];
  float* out = (float*)d_out;
  float* out_attn = out + NN * MM * DD;

  // workspace (fp32), ~4.4 MB total
  float* Wkq1    = (float*)d_ws;                      // [160][6]
  float* Wkq2    = Wkq1 + DD * 6;                     // [64][160][6]
  float* Apart   = Wkq2 + (size_t)NN * DD * 6;        // [1024][6][160]
  float* Spart   = Apart + (size_t)NN * NCHUNK * MM * DD;  // [1024][6]
  float* Sfin    = Spart + (size_t)NN * NCHUNK * MM;  // [64][6]
  float* scal    = Sfin + NN * MM;                    // [1]
  float* slotbuf = scal + 8;                          // [64][6][160]
  size_t required = (size_t)((char*)(slotbuf + NN * MM * DD) - (char*)d_ws);
  if (ws_size < required) return;

  k_init<<<16, 256, 0, stream>>>(log_tau, slots_init, q_g, q_b, Wq, Wk, Wkq1, scal);
  k_pass<false><<<NN * NCHUNK, 256, 0, stream>>>(feat, kv_g, kv_b, Wkq1, Apart, Spart, out_attn);
  k_slot<true, false><<<NN, 256, 0, stream>>>(slots_init, Apart, Spart, Wv, out_g, out_b,
                                              W1, b1, W2, b2, q_g, q_b, Wq, Wk, scal,
                                              slotbuf, Wkq2, Sfin, out);
  k_pass<true><<<NN * NCHUNK, 256, 0, stream>>>(feat, kv_g, kv_b, Wkq2, Apart, Spart, out_attn);
  k_slot<false, true><<<NN, 256, 0, stream>>>(slots_init, Apart, Spart, Wv, out_g, out_b,
                                              W1, b1, W2, b2, q_g, q_b, Wq, Wk, scal,
                                              slotbuf, Wkq2, Sfin, out);
  k_norm<<<(NN * MM * LL) / 1024, 256, 0, stream>>>(out_attn, Sfin);
}

// Round 3
// 273.513 us; speedup vs baseline: 1.8735x; 1.2752x over previous
//
#include <hip/hip_runtime.h>
#include <math.h>

#define NN 64
#define CC 160
#define LL 4096
#define DD 160
#define MM 6
#define NCHUNK 16   // chunks per image; each chunk = 256 tokens (4 tiles of 64)

__device__ __forceinline__ float bf2f(unsigned short u) {
  union { unsigned int i; float f; } v; v.i = ((unsigned int)u) << 16; return v.f;
}
__device__ __forceinline__ unsigned short f2bf(float f) {
  union { float f; unsigned int i; } v; v.f = f;
  unsigned int r = v.i + 0x7fffu + ((v.i >> 16) & 1u);
  return (unsigned short)(r >> 16);
}

// ---------------- k_init: scal = (d^-0.5 / tau); Wkq1 = scal * Wk @ q1^T ----------------
__global__ __launch_bounds__(256) void k_init(
    const float* log_tau, const float* slots_init, const float* q_g, const float* q_b,
    const float* Wq, const float* Wk, float* Wkq1, float* scal) {
  __shared__ float ln[MM * DD];
  __shared__ float qv[MM * DD];
  __shared__ float mu_s[MM], rs_s[MM];
  int tid = threadIdx.x;
  float x = log_tau[0];
  float sp = (x > 20.f) ? x : log1pf(expf(x));
  float scv = (1.0f / sqrtf((float)DD)) / (sp + 0.5f);
  if (blockIdx.x == 0 && tid == 0) scal[0] = scv;
  if (tid < MM) {
    float s = 0.f, ss = 0.f;
    for (int i = 0; i < DD; i++) { float v = slots_init[tid * DD + i]; s += v; ss += v * v; }
    float mu = s / DD, var = ss / DD - mu * mu;
    mu_s[tid] = mu; rs_s[tid] = rsqrtf(var + 1e-5f);
  }
  __syncthreads();
  for (int o = tid; o < MM * DD; o += 256) {
    int m = o / DD, d = o % DD;
    ln[o] = (slots_init[o] - mu_s[m]) * rs_s[m] * q_g[d] + q_b[d];
  }
  __syncthreads();
  for (int o = tid; o < MM * DD; o += 256) {
    int m = o / DD, d = o % DD;
    float acc = 0.f;
#pragma unroll 8
    for (int i = 0; i < DD; i++) acc += ln[m * DD + i] * Wq[i * DD + d];
    qv[o] = acc;
  }
  __syncthreads();
  for (int o = tid; o < 60; o += 256) {
    int c = blockIdx.x * 10 + o / 6, m = o % 6;
    float acc = 0.f;
#pragma unroll 8
    for (int d = 0; d < DD; d++) acc += Wk[c * DD + d] * qv[m * DD + d];
    Wkq1[c * 6 + m] = scv * acc;
  }
}

// ---------------- k_pass: fused LN + logits + softmax + weighted-token aggregation ----------------
template <bool ITER2>
__global__ __launch_bounds__(256) void k_pass(
    const float* feat, const float* kv_g, const float* kv_b,
    const float* Wkq,                       // ITER2: [n][160][6]; else shared [160][6]
    float* Apart, float* Spart, float* attn_out) {
  int b = blockIdx.x;
  int n = b >> 4, ch = b & 15;
  int tid = threadIdx.x;
  int lane = tid & 63, g = tid >> 6;
  __shared__ __align__(16) unsigned short xln[64][168];   // bf16 LN'd tile, 336B row stride
  __shared__ float att[64][6];
  __shared__ float wkq_s[160][6];
  __shared__ float part[4][64][2];
  __shared__ float mu_s[64], rs_s[64];
  __shared__ float sred[64][6];

  const float* wsrc = ITER2 ? (Wkq + (size_t)n * DD * 6) : Wkq;
  for (int o = tid; o < DD * 6; o += 256) ((float*)wkq_s)[o] = wsrc[o];

  float Aacc[6] = {0, 0, 0, 0, 0, 0};
  float Sacc[6] = {0, 0, 0, 0, 0, 0};
  __syncthreads();

  for (int t4 = 0; t4 < 4; t4++) {
    int tok0 = ch * 256 + t4 * 64;
    const float* fp = feat + ((size_t)(n * CC + g * 40)) * LL + tok0 + lane;
    float rv[40];
    float s = 0.f, ss = 0.f;
#pragma unroll
    for (int i = 0; i < 40; i++) {
      float v = fp[(size_t)i * LL];
      rv[i] = v; s += v; ss += v * v;
    }
    part[g][lane][0] = s; part[g][lane][1] = ss;
    __syncthreads();
    if (tid < 64) {
      float S = 0.f, SS = 0.f;
      for (int gg = 0; gg < 4; gg++) { S += part[gg][tid][0]; SS += part[gg][tid][1]; }
      float mu = S / CC, var = SS / CC - mu * mu;
      mu_s[tid] = mu; rs_s[tid] = rsqrtf(var + 1e-5f);
    }
    __syncthreads();
    {
      float mu = mu_s[lane], rs = rs_s[lane];
#pragma unroll
      for (int q5 = 0; q5 < 5; q5++) {
        unsigned short pk[8];
#pragma unroll
        for (int j = 0; j < 8; j++) {
          int c = g * 40 + q5 * 8 + j;
          float a = (rv[q5 * 8 + j] - mu) * rs * kv_g[c] + kv_b[c];
          pk[j] = f2bf(a);
        }
        *(uint4*)&xln[lane][g * 40 + q5 * 8] = *(const uint4*)pk;
      }
    }
    __syncthreads();
    if (tid < 128) {
      int tl = tid >> 1, hf = tid & 1;
      const unsigned short* xrow = &xln[tl][hf * 80];
      float lg[6] = {0, 0, 0, 0, 0, 0};
#pragma unroll
      for (int u = 0; u < 10; u++) {
        uint4 kv = *(const uint4*)(xrow + u * 8);
        const unsigned short* kp = (const unsigned short*)&kv;
#pragma unroll
        for (int j = 0; j < 8; j++) {
          float kf = bf2f(kp[j]);
          const float* wr = &wkq_s[hf * 80 + u * 8 + j][0];
#pragma unroll
          for (int m = 0; m < 6; m++) lg[m] += kf * wr[m];
        }
      }
#pragma unroll
      for (int m = 0; m < 6; m++) lg[m] += __shfl_xor(lg[m], 1);
      float mx = lg[0];
#pragma unroll
      for (int m = 1; m < 6; m++) mx = fmaxf(mx, lg[m]);
      float e[6], sum = 0.f;
#pragma unroll
      for (int m = 0; m < 6; m++) { e[m] = __expf(lg[m] - mx); sum += e[m]; }
      float inv = 1.0f / sum;
      if (hf == 0) {
#pragma unroll
        for (int m = 0; m < 6; m++) {
          float a = e[m] * inv;
          att[tl][m] = a;
          Sacc[m] += a;
          if (ITER2) attn_out[((size_t)(n * MM + m)) * LL + tok0 + tl] = a;
        }
      }
    }
    __syncthreads();
    if (tid < DD) {
#pragma unroll 4
      for (int t = 0; t < 64; t++) {
        float xv = bf2f(xln[t][tid]);
        float a0 = att[t][0], a1 = att[t][1], a2 = att[t][2];
        float a3 = att[t][3], a4 = att[t][4], a5 = att[t][5];
        Aacc[0] += a0 * xv; Aacc[1] += a1 * xv; Aacc[2] += a2 * xv;
        Aacc[3] += a3 * xv; Aacc[4] += a4 * xv; Aacc[5] += a5 * xv;
      }
    }
    __syncthreads();
  }
  if (tid < DD) {
#pragma unroll
    for (int m = 0; m < 6; m++) Apart[((size_t)b * 6 + m) * DD + tid] = Aacc[m];
  }
  if (tid < 128 && (tid & 1) == 0) {
#pragma unroll
    for (int m = 0; m < 6; m++) sred[tid >> 1][m] = Sacc[m];
  }
  __syncthreads();
  if (tid < 6) {
    float s = 0.f;
    for (int t = 0; t < 64; t++) s += sred[t][tid];
    Spart[b * 6 + tid] = s;
  }
}

// ---------------- k_slot2: fused per-n slot update, 512 threads, phase-parallel ----------------
template <bool FIRST, bool LAST>
__global__ __launch_bounds__(512) void k_slot2(
    const float* slots_init, const float* Apart, const float* Spart, const float* Wv,
    const float* out_g, const float* out_b,
    const float* W1, const float* b1, const float* W2, const float* b2,
    const float* q_g, const float* q_b, const float* Wq, const float* Wk, const float* scal,
    float* slotbuf, float* Wkq2, float* Sfin, float* out_slots) {
  int n = blockIdx.x;
  int tid = threadIdx.x;
  __shared__ float a_s[MM * DD];   // A-reduce; later post-MLP slots s2
  __shared__ float s1[MM * DD];    // pre-LN -> LN'd slots; later q-LN
  __shared__ float h[MM * 320];    // MLP hidden; later q
  __shared__ float Sv[MM], mu_s[MM], rs_s[MM];

  // P0: S reduce (+Sfin on LAST)
  if (tid < MM) {
    float s = 0.f;
#pragma unroll
    for (int p = 0; p < NCHUNK; p++) s += Spart[(n * NCHUNK + p) * 6 + tid];
    float sc = fmaxf(s, 1e-6f);
    Sv[tid] = sc;
    if (LAST) Sfin[n * 6 + tid] = sc;
  }
  // P1: A reduce
  for (int o = tid; o < MM * DD; o += 512) {
    float s = 0.f;
#pragma unroll
    for (int p = 0; p < NCHUNK; p++) s += Apart[(size_t)n * (NCHUNK * MM * DD) + p * (MM * DD) + o];
    a_s[o] = s;
  }
  __syncthreads();
  // P2: U = a @ Wv; slot update
  for (int o = tid; o < MM * DD; o += 512) {
    int m = o / DD, d = o % DD;
    float u = 0.f;
#pragma unroll 8
    for (int c = 0; c < DD; c++) u += a_s[m * DD + c] * Wv[c * DD + d];
    float prev = FIRST ? slots_init[o] : slotbuf[(size_t)n * MM * DD + o];
    s1[o] = prev + u / Sv[m];
  }
  __syncthreads();
  // P3: LN stats (wave m handles row m)
  if (tid < 384) {
    int m = tid >> 6, l = tid & 63;
    const float* row = &s1[m * DD];
    float s = row[l] + row[l + 64] + (l < 32 ? row[l + 128] : 0.f);
    float x0 = row[l], x1 = row[l + 64], x2 = (l < 32 ? row[l + 128] : 0.f);
    float ss = x0 * x0 + x1 * x1 + x2 * x2;
#pragma unroll
    for (int off = 32; off >= 1; off >>= 1) { s += __shfl_xor(s, off); ss += __shfl_xor(ss, off); }
    if (l == 0) {
      float mu = s / DD, var = ss / DD - mu * mu;
      mu_s[m] = mu; rs_s[m] = rsqrtf(var + 1e-5f);
    }
  }
  __syncthreads();
  // P4: apply LN
  for (int o = tid; o < MM * DD; o += 512) {
    int m = o / DD, d = o % DD;
    s1[o] = (s1[o] - mu_s[m]) * rs_s[m] * out_g[d] + out_b[d];
  }
  __syncthreads();
  // P5: MLP hidden
  for (int o = tid; o < MM * 320; o += 512) {
    int m = o / 320, j = o % 320;
    float acc = b1[j];
#pragma unroll 8
    for (int d = 0; d < DD; d++) acc += s1[m * DD + d] * W1[d * 320 + j];
    h[o] = 0.5f * acc * (1.0f + erff(acc * 0.70710678118f));
  }
  __syncthreads();
  // P6: MLP out + residual
  for (int o = tid; o < MM * DD; o += 512) {
    int m = o / DD, d = o % DD;
    float acc = b2[d];
#pragma unroll 8
    for (int j = 0; j < 320; j++) acc += h[m * 320 + j] * W2[j * DD + d];
    float val = s1[o] + acc;
    a_s[o] = val;
    if (LAST) out_slots[(size_t)n * MM * DD + o] = val;
    else slotbuf[(size_t)n * MM * DD + o] = val;
  }
  if (!LAST) {
    __syncthreads();
    // P7: LN stats on s2
    if (tid < 384) {
      int m = tid >> 6, l = tid & 63;
      const float* row = &a_s[m * DD];
      float x0 = row[l], x1 = row[l + 64], x2 = (l < 32 ? row[l + 128] : 0.f);
      float s = x0 + x1 + x2, ss = x0 * x0 + x1 * x1 + x2 * x2;
#pragma unroll
      for (int off = 32; off >= 1; off >>= 1) { s += __shfl_xor(s, off); ss += __shfl_xor(ss, off); }
      if (l == 0) {
        float mu = s / DD, var = ss / DD - mu * mu;
        mu_s[m] = mu; rs_s[m] = rsqrtf(var + 1e-5f);
      }
    }
    __syncthreads();
    // P8: q-LN
    for (int o = tid; o < MM * DD; o += 512) {
      int m = o / DD, d = o % DD;
      s1[o] = (a_s[o] - mu_s[m]) * rs_s[m] * q_g[d] + q_b[d];
    }
    __syncthreads();
    // P9: q = ln @ Wq
    for (int o = tid; o < MM * DD; o += 512) {
      int m = o / DD, d = o % DD;
      float acc = 0.f;
#pragma unroll 8
      for (int i = 0; i < DD; i++) acc += s1[m * DD + i] * Wq[i * DD + d];
      h[o] = acc;
    }
    __syncthreads();
    // P10: Wkq2[c][m] = scal * Wk[c]·q[m]
    if (tid < DD) {
      int c = tid;
      float acc[MM] = {0, 0, 0, 0, 0, 0};
#pragma unroll 4
      for (int d = 0; d < DD; d++) {
        float wk = Wk[c * DD + d];
#pragma unroll
        for (int m = 0; m < MM; m++) acc[m] += wk * h[m * DD + d];
      }
      float sc = scal[0];
#pragma unroll
      for (int m = 0; m < MM; m++) Wkq2[(size_t)n * DD * 6 + c * 6 + m] = sc * acc[m];
    }
  }
}

// ---------------- k_norm: attn_map = attn / Sfin ----------------
__global__ __launch_bounds__(256) void k_norm(float* attn, const float* Sfin) {
  int idx = blockIdx.x * 256 + threadIdx.x;
  size_t base = (size_t)idx * 4;
  int nm = (int)(base >> 12);
  float s = Sfin[nm];
  float4 v = *(float4*)(attn + base);
  float inv = 1.0f / s;
  v.x *= inv; v.y *= inv; v.z *= inv; v.w *= inv;
  *(float4*)(attn + base) = v;
}

extern "C" void kernel_launch(void* const* d_in, const int* in_sizes, int n_in,
                              void* d_out, int out_size, void* d_ws, size_t ws_size,
                              hipStream_t stream) {
  const float* feat       = (const float*)d_in[0];
  const float* slots_init = (const float*)d_in[1];
  const float* log_tau    = (const float*)d_in[2];
  const float* kv_g       = (const float*)d_in[3];
  const float* kv_b       = (const float*)d_in[4];
  const float* Wk         = (const float*)d_in[5];
  const float* Wv         = (const float*)d_in[6];
  const float* q_g        = (const float*)d_in[7];
  const float* q_b        = (const float*)d_in[8];
  const float* Wq         = (const float*)d_in[9];
  const float* out_g      = (const float*)d_in[10];
  const float* out_b      = (const float*)d_in[11];
  const float* W1         = (const float*)d_in[12];
  const float* b1         = (const float*)d_in[13];
  const float* W2         = (const float*)d_in[14];
  const float* b2         = (const float*)d_in[15];
  float* out = (float*)d_out;
  float* out_attn = out + NN * MM * DD;

  float* Wkq1    = (float*)d_ws;                      // [160][6]
  float* Wkq2    = Wkq1 + DD * 6;                     // [64][160][6]
  float* Apart   = Wkq2 + (size_t)NN * DD * 6;        // [1024][6][160]
  float* Spart   = Apart + (size_t)NN * NCHUNK * MM * DD;  // [1024][6]
  float* Sfin    = Spart + (size_t)NN * NCHUNK * MM;  // [64][6]
  float* scal    = Sfin + NN * MM;                    // [1]
  float* slotbuf = scal + 8;                          // [64][6][160]
  size_t required = (size_t)((char*)(slotbuf + NN * MM * DD) - (char*)d_ws);
  if (ws_size < required) return;

  k_init<<<16, 256, 0, stream>>>(log_tau, slots_init, q_g, q_b, Wq, Wk, Wkq1, scal);
  k_pass<false><<<NN * NCHUNK, 256, 0, stream>>>(feat, kv_g, kv_b, Wkq1, Apart, Spart, out_attn);
  k_slot2<true, false><<<NN, 512, 0, stream>>>(slots_init, Apart, Spart, Wv, out_g, out_b,
                                               W1, b1, W2, b2, q_g, q_b, Wq, Wk, scal,
                                               slotbuf, Wkq2, Sfin, out);
  k_pass<true><<<NN * NCHUNK, 256, 0, stream>>>(feat, kv_g, kv_b, Wkq2, Apart, Spart, out_attn);
  k_slot2<false, true><<<NN, 512, 0, stream>>>(slots_init, Apart, Spart, Wv, out_g, out_b,
                                               W1, b1, W2, b2, q_g, q_b, Wq, Wk, scal,
                                               slotbuf, Wkq2, Sfin, out);
  k_norm<<<(NN * MM * LL) / 1024, 256, 0, stream>>>(out_attn, Sfin);
}